// Round 1
// baseline (420.007 us; speedup 1.0000x reference)
//
#include <hip/hip_runtime.h>
#include <hip/hip_bf16.h>
#include <stdint.h>

typedef __bf16 bf16;
typedef bf16 bf16x4_t __attribute__((ext_vector_type(4)));
typedef bf16 bf16x8_t __attribute__((ext_vector_type(8)));
typedef float floatx4_t __attribute__((ext_vector_type(4)));

#define NB 8
#define SQ 2048
#define SKV 2048
#define DIN 512
#define DOUT 512

__device__ __forceinline__ void load_lds16(const bf16* g, bf16* l) {
    __builtin_amdgcn_global_load_lds(
        (const __attribute__((address_space(1))) unsigned int*)g,
        (__attribute__((address_space(3))) unsigned int*)l, 16, 0, 0);
}

// ---------------- cast fp32 -> bf16 (5 tensors) ----------------
struct CastArgs {
    const float* src[5];
    bf16* dst[5];
    int n4[5];
};
__global__ void cast_many(CastArgs a) {
    int z = blockIdx.z;
    int i = blockIdx.x * blockDim.x + threadIdx.x;
    if (i >= a.n4[z]) return;
    float4 f = ((const float4*)a.src[z])[i];
    bf16x4_t o = { (bf16)f.x, (bf16)f.y, (bf16)f.z, (bf16)f.w };
    ((bf16x4_t*)a.dst[z])[i] = o;
}

// ---------------- weight transpose f32[512,512] -> bf16 transposed ----------------
struct TWArgs { const float* src[3]; bf16* dst[3]; };
__global__ void transpose_w(TWArgs a) {
    __shared__ float t[32][33];
    const float* src = a.src[blockIdx.z];
    bf16* dst = a.dst[blockIdx.z];
    int tx = threadIdx.x, ty = threadIdx.y;
    int x0 = blockIdx.x * 32, y0 = blockIdx.y * 32;
#pragma unroll
    for (int j = 0; j < 4; ++j)
        t[ty + 8 * j][tx] = src[(y0 + ty + 8 * j) * DIN + x0 + tx];
    __syncthreads();
#pragma unroll
    for (int j = 0; j < 4; ++j)
        dst[(x0 + ty + 8 * j) * DIN + y0 + tx] = (bf16)t[tx][ty + 8 * j];
}

// ---------------- V transpose bf16 [2048,512] -> [512,2048], batched ----------------
__global__ void transpose_v(const bf16* Vb, bf16* VT) {
    __shared__ bf16 t[32][33];
    const bf16* src = Vb + (long long)blockIdx.z * SKV * DOUT;
    bf16* dst = VT + (long long)blockIdx.z * DOUT * SKV;
    int tx = threadIdx.x, ty = threadIdx.y;
    int x0 = blockIdx.x * 32, y0 = blockIdx.y * 32;
#pragma unroll
    for (int j = 0; j < 4; ++j)
        t[ty + 8 * j][tx] = src[(long long)(y0 + ty + 8 * j) * DOUT + x0 + tx];
    __syncthreads();
#pragma unroll
    for (int j = 0; j < 4; ++j)
        dst[(long long)(x0 + ty + 8 * j) * SKV + y0 + tx] = t[tx][ty + 8 * j];
}

// ---------------- row softmax in place, bf16, rows of 2048 ----------------
__global__ __launch_bounds__(256) void softmax_rows(bf16* S) {
    __shared__ float red[4];
    long long base = (long long)blockIdx.x * SKV;
    int tid = threadIdx.x;
    int lane = tid & 63, wave = tid >> 6;
    bf16x8_t v8 = *(const bf16x8_t*)&S[base + tid * 8];
    float v[8];
#pragma unroll
    for (int i = 0; i < 8; ++i) v[i] = (float)v8[i];
    float m = v[0];
#pragma unroll
    for (int i = 1; i < 8; ++i) m = fmaxf(m, v[i]);
#pragma unroll
    for (int off = 32; off > 0; off >>= 1) m = fmaxf(m, __shfl_xor(m, off, 64));
    if (lane == 0) red[wave] = m;
    __syncthreads();
    m = fmaxf(fmaxf(red[0], red[1]), fmaxf(red[2], red[3]));
    __syncthreads();
    float p[8];
    float s = 0.f;
#pragma unroll
    for (int i = 0; i < 8; ++i) { p[i] = expf(v[i] - m); s += p[i]; }
#pragma unroll
    for (int off = 32; off > 0; off >>= 1) s += __shfl_xor(s, off, 64);
    if (lane == 0) red[wave] = s;
    __syncthreads();
    s = red[0] + red[1] + red[2] + red[3];
    float inv = 1.0f / s;
    bf16x8_t o;
#pragma unroll
    for (int i = 0; i < 8; ++i) o[i] = (bf16)(p[i] * inv);
    *(bf16x8_t*)&S[base + tid * 8] = o;
}

// ---------------- NT GEMM: C[m,n] = scale * sum_k A[m,k]*B[n,k] (+ optional 2nd pair) ----------------
struct GemmArgs {
    const bf16* A; const bf16* B; void* C;
    int M, N, K;
    int lda, ldb, ldc;
    long long sA, sB, sC;
    float scale;
    const bf16* A2; const bf16* B2;
    int K2, lda2, ldb2;
    long long sA2, sB2;
};

template <bool OUT_BF16>
__global__ __launch_bounds__(256) void gemm_nt(GemmArgs g) {
    __shared__ bf16 As[128 * 32];
    __shared__ bf16 Bs[128 * 32];
    const int tid = threadIdx.x;
    const int wave = tid >> 6, lane = tid & 63;
    const int wm = (wave & 1) * 64, wn = (wave >> 1) * 64;
    const int lm = lane & 15, quad = lane >> 4;
    const long long bm = (long long)blockIdx.y * 128;
    const long long bn = (long long)blockIdx.x * 128;
    const int z = blockIdx.z;
    const int srow = lane >> 2;          // 0..15
    const int scol = (lane & 3) * 8;     // 0,8,16,24

    floatx4_t acc[4][4];
#pragma unroll
    for (int i = 0; i < 4; ++i)
#pragma unroll
        for (int j = 0; j < 4; ++j) acc[i][j] = 0.0f;

    const int npass = g.A2 ? 2 : 1;
    for (int pass = 0; pass < npass; ++pass) {
        const bf16* Ap = (pass == 0) ? g.A + (long long)z * g.sA : g.A2 + (long long)z * g.sA2;
        const bf16* Bp = (pass == 0) ? g.B + (long long)z * g.sB : g.B2 + (long long)z * g.sB2;
        const int lda = (pass == 0) ? g.lda : g.lda2;
        const int ldb = (pass == 0) ? g.ldb : g.ldb2;
        const int K = (pass == 0) ? g.K : g.K2;
        for (int k0 = 0; k0 < K; k0 += 32) {
            __syncthreads();
#pragma unroll
            for (int t = 0; t < 2; ++t) {
                const int r0 = (wave * 2 + t) * 16;
                const bf16* gp = Ap + (bm + r0 + srow) * (long long)lda + (k0 + scol);
                load_lds16(gp, &As[r0 * 32]);
            }
#pragma unroll
            for (int t = 0; t < 2; ++t) {
                const int r0 = (wave * 2 + t) * 16;
                const bf16* gp = Bp + (bn + r0 + srow) * (long long)ldb + (k0 + scol);
                load_lds16(gp, &Bs[r0 * 32]);
            }
            __syncthreads();
            bf16x8_t af[4], bfr[4];
#pragma unroll
            for (int i = 0; i < 4; ++i)
                af[i] = *(const bf16x8_t*)&As[(wm + i * 16 + lm) * 32 + quad * 8];
#pragma unroll
            for (int i = 0; i < 4; ++i)
                bfr[i] = *(const bf16x8_t*)&Bs[(wn + i * 16 + lm) * 32 + quad * 8];
#pragma unroll
            for (int i = 0; i < 4; ++i)
#pragma unroll
                for (int j = 0; j < 4; ++j)
                    acc[i][j] = __builtin_amdgcn_mfma_f32_16x16x32_bf16(af[i], bfr[j], acc[i][j], 0, 0, 0);
        }
    }

    const long long cb = (long long)z * g.sC;
#pragma unroll
    for (int i = 0; i < 4; ++i) {
#pragma unroll
        for (int j = 0; j < 4; ++j) {
            const long long row0 = bm + wm + i * 16 + quad * 4;
            const long long col = bn + wn + j * 16 + lm;
#pragma unroll
            for (int r = 0; r < 4; ++r) {
                float v = acc[i][j][r] * g.scale;
                if (OUT_BF16)
                    ((bf16*)g.C)[cb + (row0 + r) * g.ldc + col] = (bf16)v;
                else
                    ((float*)g.C)[cb + (row0 + r) * g.ldc + col] = v;
            }
        }
    }
}

extern "C" void kernel_launch(void* const* d_in, const int* in_sizes, int n_in,
                              void* d_out, int out_size, void* d_ws, size_t ws_size,
                              hipStream_t stream) {
    const float* query = (const float*)d_in[0];
    const float* key_ = (const float*)d_in[1];
    const float* value = (const float*)d_in[2];
    const float* offset = (const float*)d_in[3];
    const float* Wq = (const float*)d_in[4];
    const float* Wk = (const float*)d_in[5];
    const float* Wv = (const float*)d_in[6];
    const float* Woff = (const float*)d_in[7];
    float* out = (float*)d_out;

    char* ws = (char*)d_ws;
    const long long NE = (long long)NB * SQ * DIN;  // 8,388,608

    // workspace layout (bytes). S (67,108,864 B) overlays queryb/keyb/valueb/Vb,
    // all of which are dead by the time S is written.
    bf16* queryb  = (bf16*)(ws + 0);
    bf16* keyb    = (bf16*)(ws + 16777216);
    bf16* valueb  = (bf16*)(ws + 33554432);
    bf16* Vb      = (bf16*)(ws + 50331648);
    bf16* S       = (bf16*)(ws + 0);
    bf16* Qb      = (bf16*)(ws + 67108864);
    bf16* Kb      = (bf16*)(ws + 83886080);
    bf16* VT      = (bf16*)(ws + 100663296);
    bf16* offsetb = (bf16*)(ws + 117440512);
    bf16* G       = (bf16*)(ws + 134217728);
    bf16* WqT     = (bf16*)(ws + 138412032);
    bf16* WkT     = (bf16*)(ws + 138936320);
    bf16* WvT     = (bf16*)(ws + 139460608);
    bf16* Woffb   = (bf16*)(ws + 139984896);
    // total: 142,082,048 bytes

    // 1. casts
    CastArgs ca;
    ca.src[0] = query;  ca.dst[0] = queryb;  ca.n4[0] = (int)(NE / 4);
    ca.src[1] = key_;   ca.dst[1] = keyb;    ca.n4[1] = (int)(NE / 4);
    ca.src[2] = value;  ca.dst[2] = valueb;  ca.n4[2] = (int)(NE / 4);
    ca.src[3] = offset; ca.dst[3] = offsetb; ca.n4[3] = (int)(NE / 4);
    ca.src[4] = Woff;   ca.dst[4] = Woffb;   ca.n4[4] = (DIN * SKV) / 4;
    cast_many<<<dim3(8192, 1, 5), 256, 0, stream>>>(ca);

    // 2. weight transposes (Wq,Wk,Wv -> bf16 [N,K])
    TWArgs tw;
    tw.src[0] = Wq; tw.src[1] = Wk; tw.src[2] = Wv;
    tw.dst[0] = WqT; tw.dst[1] = WkT; tw.dst[2] = WvT;
    transpose_w<<<dim3(16, 16, 3), dim3(32, 8), 0, stream>>>(tw);

    // 3-5. projections (scale folded into Q)
    auto launch_proj = [&](const bf16* Ab, const bf16* Wt, bf16* Cb, float scale) {
        GemmArgs a = {};
        a.A = Ab; a.B = Wt; a.C = Cb;
        a.M = NB * SQ; a.N = DOUT; a.K = DIN;
        a.lda = DIN; a.ldb = DIN; a.ldc = DOUT;
        a.sA = 0; a.sB = 0; a.sC = 0;
        a.scale = scale;
        a.A2 = nullptr; a.B2 = nullptr; a.K2 = 0; a.lda2 = 0; a.ldb2 = 0; a.sA2 = 0; a.sB2 = 0;
        gemm_nt<true><<<dim3(DOUT / 128, (NB * SQ) / 128, 1), 256, 0, stream>>>(a);
    };
    launch_proj(queryb, WqT, Qb, 0.04419417382415922f);  // 1/sqrt(512)
    launch_proj(keyb, WkT, Kb, 1.0f);
    launch_proj(valueb, WvT, Vb, 1.0f);

    // 6. V transpose per batch
    transpose_v<<<dim3(DOUT / 32, SKV / 32, NB), dim3(32, 8), 0, stream>>>(Vb, VT);

    // 7. G_b = (Woff @ V_b)^T : G[n_dout, i_din] = sum_k VT[n,k] * Woff[i,k]
    {
        GemmArgs a = {};
        a.A = VT; a.B = Woffb; a.C = G;
        a.M = DOUT; a.N = DIN; a.K = SKV;
        a.lda = SKV; a.ldb = SKV; a.ldc = DIN;
        a.sA = (long long)DOUT * SKV; a.sB = 0; a.sC = (long long)DOUT * DIN;
        a.scale = 1.0f;
        a.A2 = nullptr; a.B2 = nullptr; a.K2 = 0; a.lda2 = 0; a.ldb2 = 0; a.sA2 = 0; a.sB2 = 0;
        gemm_nt<true><<<dim3(DIN / 128, DOUT / 128, NB), 256, 0, stream>>>(a);
    }

    // 8. S_b = Qb_b @ Kb_b^T (scale already in Qb)
    {
        GemmArgs a = {};
        a.A = Qb; a.B = Kb; a.C = S;
        a.M = SQ; a.N = SKV; a.K = DOUT;
        a.lda = DOUT; a.ldb = DOUT; a.ldc = SKV;
        a.sA = (long long)SQ * DOUT; a.sB = (long long)SKV * DOUT; a.sC = (long long)SQ * SKV;
        a.scale = 1.0f;
        a.A2 = nullptr; a.B2 = nullptr; a.K2 = 0; a.lda2 = 0; a.ldb2 = 0; a.sA2 = 0; a.sB2 = 0;
        gemm_nt<true><<<dim3(SKV / 128, SQ / 128, NB), 256, 0, stream>>>(a);
    }

    // 9. softmax in place
    softmax_rows<<<NB * SQ, 256, 0, stream>>>(S);

    // 10. out = P @ V + offset @ U   (fused: two NT K-loops into same accumulator)
    {
        GemmArgs a = {};
        a.A = S; a.B = VT; a.C = out;
        a.M = SQ; a.N = DOUT; a.K = SKV;
        a.lda = SKV; a.ldb = SKV; a.ldc = DOUT;
        a.sA = (long long)SQ * SKV; a.sB = (long long)DOUT * SKV; a.sC = (long long)SQ * DOUT;
        a.scale = 1.0f;
        a.A2 = offsetb; a.B2 = G;
        a.K2 = DIN; a.lda2 = DIN; a.ldb2 = DIN;
        a.sA2 = (long long)SQ * DIN; a.sB2 = (long long)DOUT * DIN;
        gemm_nt<false><<<dim3(DOUT / 128, SQ / 128, NB), 256, 0, stream>>>(a);
    }
}